// Round 5
// baseline (104.548 us; speedup 1.0000x reference)
//
#include <hip/hip_runtime.h>

#define IN_F       512
#define OUT_F      10240
#define NPROJ      6
#define THREADS    512
#define PER_T      (OUT_F / THREADS)   // 20 outputs per thread
#define GROUPS     2
#define GROUP_ROWS 4
#define ROWS       (GROUPS * GROUP_ROWS)  // 8 batch rows per block
#define NBINS      256
#define MAXLVL     4
#define CAND_CAP   64

typedef float    float4v __attribute__((ext_vector_type(4)));
typedef unsigned uint4v  __attribute__((ext_vector_type(4)));

// Gather + exact lockstep 4-row top-k select + predicated x4 store for one
// 4-row group. Thread t owns outputs [t*PER_T, t*PER_T+PER_T).
__device__ __forceinline__ void do_group(
    const float4v* __restrict__ rowT,
    const int2*    __restrict__ ip,      // proj, this thread's 60 int2
    int b0row, int batch, int k0,
    int t, int lane, int wave,
    float* __restrict__ out,
    unsigned (*s_hist4)[NBINS],
    float4v*  s_wmax4,
    unsigned (*s_bc4)[3],
    float    (*s_cand4)[CAND_CAP],
    unsigned* s_ccount4,
    float*    s_kth4)
{
    // --- gather: one ds_read_b128 per index serves all 4 rows ---
    float4v acc[PER_T];
#pragma unroll
    for (int i = 0; i < PER_T; ++i) {
        const int2 p0 = ip[i * 3 + 0];
        const int2 p1 = ip[i * 3 + 1];
        const int2 p2 = ip[i * 3 + 2];
        // same per-component summation order as rounds 1-4 (absmax 0)
        const float4v a01 = rowT[p0.x] + rowT[p0.y];
        const float4v a23 = rowT[p1.x] + rowT[p1.y];
        const float4v a45 = rowT[p2.x] + rowT[p2.y];
        acc[i] = (a01 + a23) + a45;
    }

    // --- per-row max (activations >= 0) ---
    float4v m4 = acc[0];
#pragma unroll
    for (int i = 1; i < PER_T; ++i) {
        m4.x = fmaxf(m4.x, acc[i].x);
        m4.y = fmaxf(m4.y, acc[i].y);
        m4.z = fmaxf(m4.z, acc[i].z);
        m4.w = fmaxf(m4.w, acc[i].w);
    }
#pragma unroll
    for (int d = 1; d < 64; d <<= 1) {
        m4.x = fmaxf(m4.x, __shfl_xor(m4.x, d));
        m4.y = fmaxf(m4.y, __shfl_xor(m4.y, d));
        m4.z = fmaxf(m4.z, __shfl_xor(m4.z, d));
        m4.w = fmaxf(m4.w, __shfl_xor(m4.w, d));
    }
    if (lane == 0) s_wmax4[wave] = m4;
    __syncthreads();
    float4v M4 = s_wmax4[0];
#pragma unroll
    for (int w = 1; w < THREADS / 64; ++w) {
        M4.x = fmaxf(M4.x, s_wmax4[w].x);
        M4.y = fmaxf(M4.y, s_wmax4[w].y);
        M4.z = fmaxf(M4.z, s_wmax4[w].z);
        M4.w = fmaxf(M4.w, s_wmax4[w].w);
    }

    // --- per-row selection state (all loops unrolled -> static indices) ---
    int      need[GROUP_ROWS];
    float    scl[GROUP_ROWS], off[GROUP_ROWS];
    unsigned alive[GROUP_ROWS];
    unsigned rowvalid = 0;
#pragma unroll
    for (int r = 0; r < GROUP_ROWS; ++r) {
        need[r]  = k0;
        off[r]   = 0.0f;
        alive[r] = (1u << PER_T) - 1u;
        const float Mr = M4[r];
        scl[r] = (Mr > 0.0f) ? 255.0f / Mr : 0.0f;
        if (Mr > 0.0f) rowvalid |= (1u << r);
    }
    unsigned rowactive = rowvalid;

    // --- joint refinement loop (typically exits after level 0) ---
    for (int level = 0; level < MAXLVL && rowactive; ++level) {
        ((unsigned*)&s_hist4[0][0])[t]           = 0u;
        ((unsigned*)&s_hist4[0][0])[t + THREADS] = 0u;
        __syncthreads();

#pragma unroll
        for (int r = 0; r < GROUP_ROWS; ++r) {
            if (rowactive & (1u << r)) {
#pragma unroll
                for (int i = 0; i < PER_T; ++i) {
                    if (alive[r] & (1u << i)) {
                        const float key = acc[i][r] * scl[r] - off[r];
                        int bin = (int)key;
                        bin = bin < 0 ? 0 : (bin > NBINS - 1 ? NBINS - 1 : bin);
                        atomicAdd(&s_hist4[r][bin], 1u);
                    }
                }
            }
        }
        __syncthreads();

        // 4 concurrent suffix scans: wave r handles row r (lane holds 4 bins)
        if (wave < GROUP_ROWS && (rowactive & (1u << wave))) {
            const uint4v h = ((const uint4v*)&s_hist4[wave][0])[lane];
            const unsigned s3 = h.w;
            const unsigned s2 = h.z + s3;
            const unsigned s1 = h.y + s2;
            const unsigned s0 = h.x + s1;          // quad total
            unsigned T = s0;
#pragma unroll
            for (int d = 1; d < 64; d <<= 1) {
                const unsigned o = __shfl_down(T, d);
                if (lane + d < 64) T += o;
            }
            const unsigned A = T - s0;             // sum over lanes > lane
            const int nd = (wave == 0) ? need[0] : (wave == 1) ? need[1]
                         : (wave == 2) ? need[2] : need[3];
            const unsigned S0 = A + s0, S1 = A + s1, S2 = A + s2, S3 = A + s3;
            if (h.x && (int)S0 >= nd && (int)(S0 - h.x) < nd) {
                s_bc4[wave][0] = 4u * lane + 0u; s_bc4[wave][1] = S0 - h.x; s_bc4[wave][2] = h.x;
            }
            if (h.y && (int)S1 >= nd && (int)(S1 - h.y) < nd) {
                s_bc4[wave][0] = 4u * lane + 1u; s_bc4[wave][1] = S1 - h.y; s_bc4[wave][2] = h.y;
            }
            if (h.z && (int)S2 >= nd && (int)(S2 - h.z) < nd) {
                s_bc4[wave][0] = 4u * lane + 2u; s_bc4[wave][1] = S2 - h.z; s_bc4[wave][2] = h.z;
            }
            if (h.w && (int)S3 >= nd && (int)(S3 - h.w) < nd) {
                s_bc4[wave][0] = 4u * lane + 3u; s_bc4[wave][1] = S3 - h.w; s_bc4[wave][2] = h.w;
            }
        }
        __syncthreads();

#pragma unroll
        for (int r = 0; r < GROUP_ROWS; ++r) {
            if (rowactive & (1u << r)) {
                const int      B = (int)s_bc4[r][0];
                const int  above = (int)s_bc4[r][1];
                const unsigned c = s_bc4[r][2];
                need[r] -= above;
#pragma unroll
                for (int i = 0; i < PER_T; ++i) {
                    if (alive[r] & (1u << i)) {
                        const float key = acc[i][r] * scl[r] - off[r];
                        int bin = (int)key;
                        bin = bin < 0 ? 0 : (bin > NBINS - 1 ? NBINS - 1 : bin);
                        if (bin != B) alive[r] &= ~(1u << i);
                    }
                }
                off[r] = (off[r] + (float)B) * 256.0f;
                scl[r] *= 256.0f;
                if (c <= CAND_CAP) rowactive &= ~(1u << r);
            }
        }
    }

    // --- candidates + exact rank select (original values -> exact ties) ---
    if (t < GROUP_ROWS) { s_ccount4[t] = 0u; s_kth4[t] = 0.0f; }
    __syncthreads();
#pragma unroll
    for (int r = 0; r < GROUP_ROWS; ++r) {
        if (rowvalid & (1u << r)) {
#pragma unroll
            for (int i = 0; i < PER_T; ++i) {
                if (alive[r] & (1u << i)) {
                    const unsigned idx = atomicAdd(&s_ccount4[r], 1u);
                    if (idx < CAND_CAP) s_cand4[r][idx] = acc[i][r];
                }
            }
        }
    }
    __syncthreads();
    if (wave < GROUP_ROWS && (rowvalid & (1u << wave))) {
        const unsigned c = s_ccount4[wave];
        const int nd = (wave == 0) ? need[0] : (wave == 1) ? need[1]
                     : (wave == 2) ? need[2] : need[3];
        if (c > CAND_CAP) {
            // values within a sub-ulp span after refinement: treat as ties
            if (lane == 0) s_kth4[wave] = s_cand4[wave][0];
        } else if (lane < (int)c) {
            const float v = s_cand4[wave][lane];
            int gt = 0, eq = 0;
            for (unsigned j = 0; j < c; ++j) {
                const float u = s_cand4[wave][j];
                gt += (u > v);
                eq += (u == v);
            }
            if (gt < nd && gt + eq >= nd) s_kth4[wave] = v;  // ties write same value
        }
    }
    __syncthreads();
    const float4v kth4 = { s_kth4[0], s_kth4[1], s_kth4[2], s_kth4[3] };

    // --- predicated stores: 5 x dwordx4 per row (thread-contiguous outputs) ---
#pragma unroll
    for (int r = 0; r < GROUP_ROWS; ++r) {
        const int br = b0row + r;
        if (br < batch) {
            float4v* orow = (float4v*)(out + (size_t)br * OUT_F + (size_t)t * PER_T);
#pragma unroll
            for (int p = 0; p < PER_T / 4; ++p) {
                float4v w;
                const float v0 = acc[4 * p + 0][r];
                const float v1 = acc[4 * p + 1][r];
                const float v2 = acc[4 * p + 2][r];
                const float v3 = acc[4 * p + 3][r];
                w.x = (v0 >= kth4[r]) ? v0 : 0.0f;
                w.y = (v1 >= kth4[r]) ? v1 : 0.0f;
                w.z = (v2 >= kth4[r]) ? v2 : 0.0f;
                w.w = (v3 >= kth4[r]) ? v3 : 0.0f;
                orow[p] = w;
            }
        }
    }
}

// One block = 8 batch rows, processed as two pipelined 4-row groups.
// G0's HBM stores (fire-and-forget) drain under G1's LDS gather+select.
__global__ __launch_bounds__(THREADS, 4) void flyhash_wta_kernel(
    const float* __restrict__ inp,
    const int*   __restrict__ proj,
    const int*   __restrict__ hlen,
    float*       __restrict__ out,
    int batch)
{
    __shared__ float4v             s_rowT[GROUPS][IN_F];      // 16 KB
    __shared__ __align__(16) unsigned s_hist4[GROUP_ROWS][NBINS]; // 4 KB
    __shared__ float4v             s_wmax4[THREADS / 64];
    __shared__ unsigned            s_bc4[GROUP_ROWS][3];
    __shared__ float               s_cand4[GROUP_ROWS][CAND_CAP];
    __shared__ unsigned            s_ccount4[GROUP_ROWS];
    __shared__ float               s_kth4[GROUP_ROWS];

    const int t    = threadIdx.x;
    const int lane = t & 63;
    const int wave = t >> 6;
    const int b0   = blockIdx.x * ROWS;

    // --- stage both groups transposed; LDS writes linear (addr_dw = c*4+r) ---
    {
        const int r     = t & 3;
        const int cbase = t >> 2;
#pragma unroll
        for (int g = 0; g < GROUPS; ++g) {
            int br = b0 + g * GROUP_ROWS + r;
            if (br >= batch) br = batch - 1;       // clamp (reads only)
            const float* grow = inp + (size_t)br * IN_F;
#pragma unroll
            for (int p = 0; p < IN_F / (THREADS / 4); ++p) {   // 4
                const int c = cbase + p * (THREADS / 4);
                ((float*)&s_rowT[g][0])[c * 4 + r] = grow[c];
            }
        }
    }
    __syncthreads();

    const int k0 = hlen[0];
    const int2* ip = (const int2*)proj + (size_t)t * (PER_T * NPROJ / 2);

    do_group(&s_rowT[0][0], ip, b0,              batch, k0, t, lane, wave, out,
             s_hist4, s_wmax4, s_bc4, s_cand4, s_ccount4, s_kth4);
    do_group(&s_rowT[1][0], ip, b0 + GROUP_ROWS, batch, k0, t, lane, wave, out,
             s_hist4, s_wmax4, s_bc4, s_cand4, s_ccount4, s_kth4);
}

extern "C" void kernel_launch(void* const* d_in, const int* in_sizes, int n_in,
                              void* d_out, int out_size, void* d_ws, size_t ws_size,
                              hipStream_t stream) {
    const float* inp  = (const float*)d_in[0];
    const int*   proj = (const int*)d_in[1];
    const int*   hlen = (const int*)d_in[2];
    float*       out  = (float*)d_out;

    const int batch  = in_sizes[0] / IN_F;            // 4096
    const int blocks = (batch + ROWS - 1) / ROWS;     // 512

    hipLaunchKernelGGL(flyhash_wta_kernel, dim3(blocks), dim3(THREADS), 0, stream,
                       inp, proj, hlen, out, batch);
}

// Round 6
// 84.655 us; speedup vs baseline: 1.2350x; 1.2350x over previous
//
#include <hip/hip_runtime.h>

#define IN_F       512
#define OUT_F      10240
#define NPROJ      6
#define THREADS    512
#define PER_T      (OUT_F / THREADS)   // 20 outputs per thread
#define GROUPS     2
#define GROUP_ROWS 4
#define ROWS       (GROUPS * GROUP_ROWS)  // 8 batch rows per block
#define NBINS      256
#define MAXLVL     4
#define CAND_CAP   64

typedef float    float4v __attribute__((ext_vector_type(4)));
typedef unsigned uint4v  __attribute__((ext_vector_type(4)));

// Gather + exact lockstep 4-row top-k select + predicated coalesced store for
// one 4-row group. Output o = t + i*THREADS (round-4 layout: per-instruction
// lane-contiguous stores and 24B-stride proj loads).
__device__ __forceinline__ void do_group(
    const float4v* __restrict__ rowT,
    const int*     __restrict__ proj,
    int b0row, int batch, int k0,
    int t, int lane, int wave,
    float* __restrict__ out,
    unsigned (*s_hist4)[NBINS],
    float4v*  s_wmax4,
    unsigned (*s_bc4)[3],
    float    (*s_cand4)[CAND_CAP],
    unsigned* s_ccount4,
    float*    s_kth4)
{
    // --- gather: one ds_read_b128 per index serves all 4 rows ---
    float4v acc[PER_T];
#pragma unroll
    for (int i = 0; i < PER_T; ++i) {
        const int o = t + i * THREADS;
        const int2* ip = (const int2*)(proj + (size_t)o * NPROJ);
        const int2 p0 = ip[0];
        const int2 p1 = ip[1];
        const int2 p2 = ip[2];
        // same per-component summation order as rounds 1-5 (absmax 0)
        const float4v a01 = rowT[p0.x] + rowT[p0.y];
        const float4v a23 = rowT[p1.x] + rowT[p1.y];
        const float4v a45 = rowT[p2.x] + rowT[p2.y];
        acc[i] = (a01 + a23) + a45;
    }

    // --- per-row max (activations >= 0) ---
    float4v m4 = acc[0];
#pragma unroll
    for (int i = 1; i < PER_T; ++i) {
        m4.x = fmaxf(m4.x, acc[i].x);
        m4.y = fmaxf(m4.y, acc[i].y);
        m4.z = fmaxf(m4.z, acc[i].z);
        m4.w = fmaxf(m4.w, acc[i].w);
    }
#pragma unroll
    for (int d = 1; d < 64; d <<= 1) {
        m4.x = fmaxf(m4.x, __shfl_xor(m4.x, d));
        m4.y = fmaxf(m4.y, __shfl_xor(m4.y, d));
        m4.z = fmaxf(m4.z, __shfl_xor(m4.z, d));
        m4.w = fmaxf(m4.w, __shfl_xor(m4.w, d));
    }
    if (lane == 0) s_wmax4[wave] = m4;
    __syncthreads();
    float4v M4 = s_wmax4[0];
#pragma unroll
    for (int w = 1; w < THREADS / 64; ++w) {
        M4.x = fmaxf(M4.x, s_wmax4[w].x);
        M4.y = fmaxf(M4.y, s_wmax4[w].y);
        M4.z = fmaxf(M4.z, s_wmax4[w].z);
        M4.w = fmaxf(M4.w, s_wmax4[w].w);
    }

    // --- per-row selection state (all loops unrolled -> static indices) ---
    int      need[GROUP_ROWS];
    float    scl[GROUP_ROWS], off[GROUP_ROWS];
    unsigned alive[GROUP_ROWS];
    unsigned rowvalid = 0;
#pragma unroll
    for (int r = 0; r < GROUP_ROWS; ++r) {
        need[r]  = k0;
        off[r]   = 0.0f;
        alive[r] = (1u << PER_T) - 1u;
        const float Mr = M4[r];
        scl[r] = (Mr > 0.0f) ? 255.0f / Mr : 0.0f;
        if (Mr > 0.0f) rowvalid |= (1u << r);
    }
    unsigned rowactive = rowvalid;

    // --- joint refinement loop (typically exits after level 0) ---
    for (int level = 0; level < MAXLVL && rowactive; ++level) {
        ((unsigned*)&s_hist4[0][0])[t]           = 0u;
        ((unsigned*)&s_hist4[0][0])[t + THREADS] = 0u;
        __syncthreads();

#pragma unroll
        for (int r = 0; r < GROUP_ROWS; ++r) {
            if (rowactive & (1u << r)) {
#pragma unroll
                for (int i = 0; i < PER_T; ++i) {
                    if (alive[r] & (1u << i)) {
                        const float key = acc[i][r] * scl[r] - off[r];
                        int bin = (int)key;
                        bin = bin < 0 ? 0 : (bin > NBINS - 1 ? NBINS - 1 : bin);
                        atomicAdd(&s_hist4[r][bin], 1u);
                    }
                }
            }
        }
        __syncthreads();

        // 4 concurrent suffix scans: wave r handles row r (lane holds 4 bins)
        if (wave < GROUP_ROWS && (rowactive & (1u << wave))) {
            const uint4v h = ((const uint4v*)&s_hist4[wave][0])[lane];
            const unsigned s3 = h.w;
            const unsigned s2 = h.z + s3;
            const unsigned s1 = h.y + s2;
            const unsigned s0 = h.x + s1;          // quad total
            unsigned T = s0;
#pragma unroll
            for (int d = 1; d < 64; d <<= 1) {
                const unsigned o = __shfl_down(T, d);
                if (lane + d < 64) T += o;
            }
            const unsigned A = T - s0;             // sum over lanes > lane
            const int nd = (wave == 0) ? need[0] : (wave == 1) ? need[1]
                         : (wave == 2) ? need[2] : need[3];
            const unsigned S0 = A + s0, S1 = A + s1, S2 = A + s2, S3 = A + s3;
            if (h.x && (int)S0 >= nd && (int)(S0 - h.x) < nd) {
                s_bc4[wave][0] = 4u * lane + 0u; s_bc4[wave][1] = S0 - h.x; s_bc4[wave][2] = h.x;
            }
            if (h.y && (int)S1 >= nd && (int)(S1 - h.y) < nd) {
                s_bc4[wave][0] = 4u * lane + 1u; s_bc4[wave][1] = S1 - h.y; s_bc4[wave][2] = h.y;
            }
            if (h.z && (int)S2 >= nd && (int)(S2 - h.z) < nd) {
                s_bc4[wave][0] = 4u * lane + 2u; s_bc4[wave][1] = S2 - h.z; s_bc4[wave][2] = h.z;
            }
            if (h.w && (int)S3 >= nd && (int)(S3 - h.w) < nd) {
                s_bc4[wave][0] = 4u * lane + 3u; s_bc4[wave][1] = S3 - h.w; s_bc4[wave][2] = h.w;
            }
        }
        __syncthreads();

#pragma unroll
        for (int r = 0; r < GROUP_ROWS; ++r) {
            if (rowactive & (1u << r)) {
                const int      B = (int)s_bc4[r][0];
                const int  above = (int)s_bc4[r][1];
                const unsigned c = s_bc4[r][2];
                need[r] -= above;
#pragma unroll
                for (int i = 0; i < PER_T; ++i) {
                    if (alive[r] & (1u << i)) {
                        const float key = acc[i][r] * scl[r] - off[r];
                        int bin = (int)key;
                        bin = bin < 0 ? 0 : (bin > NBINS - 1 ? NBINS - 1 : bin);
                        if (bin != B) alive[r] &= ~(1u << i);
                    }
                }
                off[r] = (off[r] + (float)B) * 256.0f;
                scl[r] *= 256.0f;
                if (c <= CAND_CAP) rowactive &= ~(1u << r);
            }
        }
    }

    // --- candidates + exact rank select (original values -> exact ties) ---
    if (t < GROUP_ROWS) { s_ccount4[t] = 0u; s_kth4[t] = 0.0f; }
    __syncthreads();
#pragma unroll
    for (int r = 0; r < GROUP_ROWS; ++r) {
        if (rowvalid & (1u << r)) {
#pragma unroll
            for (int i = 0; i < PER_T; ++i) {
                if (alive[r] & (1u << i)) {
                    const unsigned idx = atomicAdd(&s_ccount4[r], 1u);
                    if (idx < CAND_CAP) s_cand4[r][idx] = acc[i][r];
                }
            }
        }
    }
    __syncthreads();
    if (wave < GROUP_ROWS && (rowvalid & (1u << wave))) {
        const unsigned c = s_ccount4[wave];
        const int nd = (wave == 0) ? need[0] : (wave == 1) ? need[1]
                     : (wave == 2) ? need[2] : need[3];
        if (c > CAND_CAP) {
            // values within a sub-ulp span after refinement: treat as ties
            if (lane == 0) s_kth4[wave] = s_cand4[wave][0];
        } else if (lane < (int)c) {
            const float v = s_cand4[wave][lane];
            int gt = 0, eq = 0;
            for (unsigned j = 0; j < c; ++j) {
                const float u = s_cand4[wave][j];
                gt += (u > v);
                eq += (u == v);
            }
            if (gt < nd && gt + eq >= nd) s_kth4[wave] = v;  // ties write same value
        }
    }
    __syncthreads();
    const float4v kth4 = { s_kth4[0], s_kth4[1], s_kth4[2], s_kth4[3] };

    // --- predicated coalesced stores (round-4 layout: contiguous per instr) ---
#pragma unroll
    for (int r = 0; r < GROUP_ROWS; ++r) {
        const int br = b0row + r;
        if (br < batch) {
            float* orow = out + (size_t)br * OUT_F;
#pragma unroll
            for (int i = 0; i < PER_T; ++i) {
                const float v = acc[i][r];
                orow[t + i * THREADS] = (v >= kth4[r]) ? v : 0.0f;
            }
        }
    }
}

// One block = 8 batch rows, processed as two pipelined 4-row groups.
// G0's HBM stores (fire-and-forget) drain under G1's LDS gather+select.
__global__ __launch_bounds__(THREADS, 4) void flyhash_wta_kernel(
    const float* __restrict__ inp,
    const int*   __restrict__ proj,
    const int*   __restrict__ hlen,
    float*       __restrict__ out,
    int batch)
{
    __shared__ float4v             s_rowT[GROUPS][IN_F];      // 16 KB
    __shared__ __align__(16) unsigned s_hist4[GROUP_ROWS][NBINS]; // 4 KB
    __shared__ float4v             s_wmax4[THREADS / 64];
    __shared__ unsigned            s_bc4[GROUP_ROWS][3];
    __shared__ float               s_cand4[GROUP_ROWS][CAND_CAP];
    __shared__ unsigned            s_ccount4[GROUP_ROWS];
    __shared__ float               s_kth4[GROUP_ROWS];

    const int t    = threadIdx.x;
    const int lane = t & 63;
    const int wave = t >> 6;
    const int b0   = blockIdx.x * ROWS;

    // --- stage both groups transposed; LDS writes linear (addr_dw = c*4+r) ---
    {
        const int r     = t & 3;
        const int cbase = t >> 2;
#pragma unroll
        for (int g = 0; g < GROUPS; ++g) {
            int br = b0 + g * GROUP_ROWS + r;
            if (br >= batch) br = batch - 1;       // clamp (reads only)
            const float* grow = inp + (size_t)br * IN_F;
#pragma unroll
            for (int p = 0; p < IN_F / (THREADS / 4); ++p) {   // 4
                const int c = cbase + p * (THREADS / 4);
                ((float*)&s_rowT[g][0])[c * 4 + r] = grow[c];
            }
        }
    }
    __syncthreads();

    const int k0 = hlen[0];

    do_group(&s_rowT[0][0], proj, b0,              batch, k0, t, lane, wave, out,
             s_hist4, s_wmax4, s_bc4, s_cand4, s_ccount4, s_kth4);
    do_group(&s_rowT[1][0], proj, b0 + GROUP_ROWS, batch, k0, t, lane, wave, out,
             s_hist4, s_wmax4, s_bc4, s_cand4, s_ccount4, s_kth4);
}

extern "C" void kernel_launch(void* const* d_in, const int* in_sizes, int n_in,
                              void* d_out, int out_size, void* d_ws, size_t ws_size,
                              hipStream_t stream) {
    const float* inp  = (const float*)d_in[0];
    const int*   proj = (const int*)d_in[1];
    const int*   hlen = (const int*)d_in[2];
    float*       out  = (float*)d_out;

    const int batch  = in_sizes[0] / IN_F;            // 4096
    const int blocks = (batch + ROWS - 1) / ROWS;     // 512

    hipLaunchKernelGGL(flyhash_wta_kernel, dim3(blocks), dim3(THREADS), 0, stream,
                       inp, proj, hlen, out, batch);
}

// Round 7
// 56.102 us; speedup vs baseline: 1.8635x; 1.5089x over previous
//
#include <hip/hip_runtime.h>

#define IN_F     512
#define OUT_F    10240
#define NPROJ    6
#define THREADS  512
#define PER_T    (OUT_F / THREADS)   // 20 outputs per thread
#define ROWS     4                   // batch rows per block
#define NBINS    256
#define CAND_CAP 128
#define NWAVES   (THREADS / 64)
#define FLT_BIG  3.402823466e+38f

typedef float    float4v __attribute__((ext_vector_type(4)));
typedef unsigned uint4v  __attribute__((ext_vector_type(4)));

// One block = 4 batch rows (round-4 structure, new cheap selection).
// Selection: per-thread max -> 512-max histogram (4 atomics/thread) ->
// suffix scan -> T = min qualifying max (provable lower bound on kth) ->
// collect candidates >= T -> exact rank select on original values.
// Fallback (pathological ties only): exact uint bisection on count(>=x).
__global__ __launch_bounds__(THREADS, 4) void flyhash_wta_kernel(
    const float* __restrict__ inp,
    const int*   __restrict__ proj,
    const int*   __restrict__ hlen,
    float*       __restrict__ out,
    int batch)
{
    __shared__ float4v  s_rowT[IN_F];             // 8 KB transposed tile
    __shared__ unsigned s_hist[ROWS][NBINS];      // 4 KB thread-max histogram
    __shared__ float4v  s_red[NWAVES];            // reduce scratch
    __shared__ unsigned s_bin[ROWS];
    __shared__ float    s_cand[ROWS][CAND_CAP];   // 2 KB
    __shared__ unsigned s_cnt[ROWS];
    __shared__ float    s_kth[ROWS];
    __shared__ int      s_pc[ROWS][NWAVES];       // bisection partial counts

    const int t    = threadIdx.x;
    const int lane = t & 63;
    const int wave = t >> 6;
    const int b0   = blockIdx.x * ROWS;

    // --- stage 4 rows transposed (linear LDS writes); zero small state ---
    {
        const int r  = t & 3;
        const int cb = t >> 2;
        int br = b0 + r;
        if (br >= batch) br = batch - 1;           // clamp (reads only)
        const float* g = inp + (size_t)br * IN_F;
#pragma unroll
        for (int p = 0; p < 4; ++p) {
            const int c = cb + p * (THREADS / 4);
            ((float*)s_rowT)[c * 4 + r] = g[c];
        }
    }
    ((unsigned*)s_hist)[t]           = 0u;
    ((unsigned*)s_hist)[t + THREADS] = 0u;
    if (t < ROWS) { s_cnt[t] = 0u; s_kth[t] = 0.0f; }
    __syncthreads();

    const int k0 = hlen[0];

    // --- gather: one ds_read_b128 per index serves all 4 rows (round-4) ---
    float4v acc[PER_T];
#pragma unroll
    for (int i = 0; i < PER_T; ++i) {
        const int o = t + i * THREADS;
        const int2* ip = (const int2*)(proj + (size_t)o * NPROJ);
        const int2 p0 = ip[0];
        const int2 p1 = ip[1];
        const int2 p2 = ip[2];
        // same per-component summation order as rounds 1-6 (absmax 0)
        const float4v a01 = s_rowT[p0.x] + s_rowT[p0.y];
        const float4v a23 = s_rowT[p1.x] + s_rowT[p1.y];
        const float4v a45 = s_rowT[p2.x] + s_rowT[p2.y];
        acc[i] = (a01 + a23) + a45;
    }

    // --- per-thread per-row max ---
    float4v tmax = acc[0];
#pragma unroll
    for (int i = 1; i < PER_T; ++i) {
        tmax.x = fmaxf(tmax.x, acc[i].x);
        tmax.y = fmaxf(tmax.y, acc[i].y);
        tmax.z = fmaxf(tmax.z, acc[i].z);
        tmax.w = fmaxf(tmax.w, acc[i].w);
    }

    // --- block max M4 ---
    float4v m4 = tmax;
#pragma unroll
    for (int d = 1; d < 64; d <<= 1) {
        m4.x = fmaxf(m4.x, __shfl_xor(m4.x, d));
        m4.y = fmaxf(m4.y, __shfl_xor(m4.y, d));
        m4.z = fmaxf(m4.z, __shfl_xor(m4.z, d));
        m4.w = fmaxf(m4.w, __shfl_xor(m4.w, d));
    }
    if (lane == 0) s_red[wave] = m4;
    __syncthreads();
    float4v M4 = s_red[0];
#pragma unroll
    for (int w = 1; w < NWAVES; ++w) {
        M4.x = fmaxf(M4.x, s_red[w].x);
        M4.y = fmaxf(M4.y, s_red[w].y);
        M4.z = fmaxf(M4.z, s_red[w].z);
        M4.w = fmaxf(M4.w, s_red[w].w);
    }

    // --- histogram of thread-maxes: 4 atomics/thread total ---
    unsigned rowvalid = 0;
    int bin_[ROWS];
#pragma unroll
    for (int r = 0; r < ROWS; ++r) {
        const float Mr = M4[r];
        const float scl = (Mr > 0.0f) ? 255.0f / Mr : 0.0f;
        int b = (int)(tmax[r] * scl);
        b = b < 0 ? 0 : (b > NBINS - 1 ? NBINS - 1 : b);
        bin_[r] = b;
        if (Mr > 0.0f) {
            rowvalid |= (1u << r);
            atomicAdd(&s_hist[r][b], 1u);
        }
    }
    __syncthreads();

    // --- suffix scan on max-histogram: wave r -> row r ---
    if (wave < ROWS && (rowvalid & (1u << wave))) {
        const uint4v h = ((const uint4v*)&s_hist[wave][0])[lane];
        const unsigned s3 = h.w;
        const unsigned s2 = h.z + s3;
        const unsigned s1 = h.y + s2;
        const unsigned s0 = h.x + s1;
        unsigned T = s0;
#pragma unroll
        for (int d = 1; d < 64; d <<= 1) {
            const unsigned o = __shfl_down(T, d);
            if (lane + d < 64) T += o;
        }
        const unsigned A = T - s0;                 // sum over lanes > lane
        const unsigned S0 = A + s0, S1 = A + s1, S2 = A + s2, S3 = A + s3;
        if (h.x && (int)S0 >= k0 && (int)(S0 - h.x) < k0) s_bin[wave] = 4u * lane + 0u;
        if (h.y && (int)S1 >= k0 && (int)(S1 - h.y) < k0) s_bin[wave] = 4u * lane + 1u;
        if (h.z && (int)S2 >= k0 && (int)(S2 - h.z) < k0) s_bin[wave] = 4u * lane + 2u;
        if (h.w && (int)S3 >= k0 && (int)(S3 - h.w) < k0) s_bin[wave] = 4u * lane + 3u;
        if (lane == 0 && (int)(A + s0) < k0) s_bin[wave] = 0u;   // k > #maxes
    }
    __syncthreads();

    // --- T4 = min over qualifying thread-maxes (bin >= selected bin) ---
    float4v q4;
#pragma unroll
    for (int r = 0; r < ROWS; ++r)
        q4[r] = (((rowvalid >> r) & 1u) && bin_[r] >= (int)s_bin[r]) ? tmax[r] : FLT_BIG;
#pragma unroll
    for (int d = 1; d < 64; d <<= 1) {
        q4.x = fminf(q4.x, __shfl_xor(q4.x, d));
        q4.y = fminf(q4.y, __shfl_xor(q4.y, d));
        q4.z = fminf(q4.z, __shfl_xor(q4.z, d));
        q4.w = fminf(q4.w, __shfl_xor(q4.w, d));
    }
    if (lane == 0) s_red[wave] = q4;
    __syncthreads();
    float4v T4 = s_red[0];
#pragma unroll
    for (int w = 1; w < NWAVES; ++w) {
        T4.x = fminf(T4.x, s_red[w].x);
        T4.y = fminf(T4.y, s_red[w].y);
        T4.z = fminf(T4.z, s_red[w].z);
        T4.w = fminf(T4.w, s_red[w].w);
    }

    // --- collect candidates >= T (sparse atomics; exact original values) ---
#pragma unroll
    for (int i = 0; i < PER_T; ++i) {
#pragma unroll
        for (int r = 0; r < ROWS; ++r) {
            const float v = acc[i][r];
            if (v >= T4[r]) {
                const unsigned idx = atomicAdd(&s_cnt[r], 1u);
                if (idx < CAND_CAP) s_cand[r][idx] = v;
            }
        }
    }
    __syncthreads();

    // --- overflow fallback: exact uint bisection on count(>=x) (rare) ---
    unsigned ovf = 0;
#pragma unroll
    for (int r = 0; r < ROWS; ++r)
        if (((rowvalid >> r) & 1u) && s_cnt[r] > CAND_CAP) ovf |= (1u << r);

    if (ovf) {
        unsigned lo[ROWS], hi[ROWS];
#pragma unroll
        for (int r = 0; r < ROWS; ++r) {
            lo[r] = __float_as_uint(T4[r]);        // count(>=lo) >= k
            hi[r] = __float_as_uint(M4[r]) + 1u;   // count(>=hi) == 0 < k
        }
        for (int it = 0; it < 34; ++it) {
            unsigned work = 0;
#pragma unroll
            for (int r = 0; r < ROWS; ++r)
                if (((ovf >> r) & 1u) && hi[r] - lo[r] > 1u) work |= (1u << r);
            if (!work) break;
            unsigned mid[ROWS];
#pragma unroll
            for (int r = 0; r < ROWS; ++r) mid[r] = lo[r] + (hi[r] - lo[r]) / 2u;
            int c0 = 0, c1 = 0, c2 = 0, c3 = 0;
#pragma unroll
            for (int i = 0; i < PER_T; ++i) {
                c0 += (__float_as_uint(acc[i].x) >= mid[0]);
                c1 += (__float_as_uint(acc[i].y) >= mid[1]);
                c2 += (__float_as_uint(acc[i].z) >= mid[2]);
                c3 += (__float_as_uint(acc[i].w) >= mid[3]);
            }
#pragma unroll
            for (int d = 1; d < 64; d <<= 1) {
                c0 += __shfl_xor(c0, d);
                c1 += __shfl_xor(c1, d);
                c2 += __shfl_xor(c2, d);
                c3 += __shfl_xor(c3, d);
            }
            if (lane == 0) {
                s_pc[0][wave] = c0; s_pc[1][wave] = c1;
                s_pc[2][wave] = c2; s_pc[3][wave] = c3;
            }
            __syncthreads();
#pragma unroll
            for (int r = 0; r < ROWS; ++r) {
                if ((work >> r) & 1u) {
                    int c = 0;
#pragma unroll
                    for (int w = 0; w < NWAVES; ++w) c += s_pc[r][w];
                    if (c >= k0) lo[r] = mid[r]; else hi[r] = mid[r];
                }
            }
            __syncthreads();
        }
        if (t == 0) {
#pragma unroll
            for (int r = 0; r < ROWS; ++r)
                if ((ovf >> r) & 1u) s_kth[r] = __uint_as_float(lo[r]);
        }
    }

    // --- exact rank select over candidates: wave r -> row r ---
    if (wave < ROWS && (rowvalid & (1u << wave)) && !((ovf >> wave) & 1u)) {
        const unsigned c = s_cnt[wave];
        for (unsigned s = lane; s < c; s += 64) {
            const float v = s_cand[wave][s];
            int gt = 0, eq = 0;
            for (unsigned j = 0; j < c; ++j) {
                const float u = s_cand[wave][j];
                gt += (u > v);
                eq += (u == v);
            }
            if (gt < k0 && gt + eq >= k0) s_kth[wave] = v;   // ties write same value
        }
    }
    __syncthreads();
    const float4v kth4 = { s_kth[0], s_kth[1], s_kth[2], s_kth[3] };

    // --- predicated coalesced stores (round-4 layout) ---
#pragma unroll
    for (int r = 0; r < ROWS; ++r) {
        const int br = b0 + r;
        if (br < batch) {
            float* orow = out + (size_t)br * OUT_F;
#pragma unroll
            for (int i = 0; i < PER_T; ++i) {
                const float v = acc[i][r];
                orow[t + i * THREADS] = (v >= kth4[r]) ? v : 0.0f;
            }
        }
    }
}

extern "C" void kernel_launch(void* const* d_in, const int* in_sizes, int n_in,
                              void* d_out, int out_size, void* d_ws, size_t ws_size,
                              hipStream_t stream) {
    const float* inp  = (const float*)d_in[0];
    const int*   proj = (const int*)d_in[1];
    const int*   hlen = (const int*)d_in[2];
    float*       out  = (float*)d_out;

    const int batch  = in_sizes[0] / IN_F;            // 4096
    const int blocks = (batch + ROWS - 1) / ROWS;     // 1024

    hipLaunchKernelGGL(flyhash_wta_kernel, dim3(blocks), dim3(THREADS), 0, stream,
                       inp, proj, hlen, out, batch);
}